// Round 3
// baseline (3478.148 us; speedup 1.0000x reference)
//
#include <hip/hip_runtime.h>
#include <stdint.h>

// RotEncoderMLP: orbit-stack -> c4conv(7->2048)+relu -> c4conv(2048->2048)+LN+relu -> c4conv(2048->512)
// All c4convs are GEMMs vs block-circulant weights: Bt[(g,i)][(h,j)] = w[(h-g)&3][i][j].
// L2/L3: bf16 MFMA GEMM, 128x128 tile, BK=64, global_load_lds w=16.
// R3 change: LDS tiles stored in MFMA-FRAGMENT order (As[half][mi][ks][lane][8]) so every
// ds_read_b128 is lane-contiguous -> zero bank conflicts (R2 counters: 2.5e8 conflicts/dispatch
// from 128B-row-stride 16-way aliasing). Staging permutes per-lane SOURCE addresses instead
// (global_load_lds LDS dest is fixed at wave-base + lane*16).

#define HID 2048
#define KDIM 8192
#define MROWS 10240

typedef float floatx4 __attribute__((ext_vector_type(4)));
typedef __bf16 bf16x8 __attribute__((ext_vector_type(8)));

__device__ __forceinline__ unsigned short f2bf(float f) {
  union { float f; unsigned int u; } v; v.f = f;
  unsigned int r = v.u + 0x7fffu + ((v.u >> 16) & 1u);  // RNE
  return (unsigned short)(r >> 16);
}

// ---------- f32 -> bf16 weight convert ----------
__global__ __launch_bounds__(256) void cvt_bf16_kernel(const float* __restrict__ s,
                                                       unsigned short* __restrict__ d, int n4) {
  int i = blockIdx.x * 256 + threadIdx.x;
  if (i >= n4) return;
  float4 v = ((const float4*)s)[i];
  ushort4 o;
  o.x = f2bf(v.x); o.y = f2bf(v.y); o.z = f2bf(v.z); o.w = f2bf(v.w);
  ((ushort4*)d)[i] = o;
}

// ---------- orbit-stack + layer1 + relu -> h1 bf16 (chunk-local rows x 8192; col = g*2048+i) ----------
__global__ __launch_bounds__(256) void layer1_kernel(const float* __restrict__ ins,
                                                     const float* __restrict__ w1,
                                                     const float* __restrict__ b1,
                                                     unsigned short* __restrict__ h1,
                                                     int row0) {
  __shared__ float orbs[32][28];
  int t = threadIdx.x;
  int b0 = blockIdx.x * 32;            // chunk-local
  int g = blockIdx.y >> 3;
  int i = (blockIdx.y & 7) * 256 + t;
  if (t < 32) {
    const float* x = ins + (size_t)(row0 + b0 + t) * 25;
    float v[25];
#pragma unroll
    for (int p = 0; p < 25; ++p) v[p] = x[p];
    float* o = orbs[t];
    o[0] = v[12]; o[7] = v[12]; o[14] = v[12]; o[21] = v[12];  // center, all 4 rotations
#pragma unroll
    for (int r = 0; r < 2; ++r)
#pragma unroll
      for (int c = 0; c < 3; ++c) {
        int m = 1 + r * 3 + c;
        o[m]      = v[r * 5 + c];              // rot^0: x[r][c]
        o[7 + m]  = v[c * 5 + (4 - r)];        // rot^1: x[c][4-r]
        o[14 + m] = v[(4 - r) * 5 + (4 - c)];  // rot^2
        o[21 + m] = v[(4 - c) * 5 + r];        // rot^3
      }
  }
  __syncthreads();
  float w[4][7];
#pragma unroll
  for (int r = 0; r < 4; ++r)
#pragma unroll
    for (int j = 0; j < 7; ++j) w[r][j] = w1[(r * HID + i) * 7 + j];
  float bias = b1[i];
  for (int s = 0; s < 32; ++s) {
    float acc = bias;
#pragma unroll
    for (int hh = 0; hh < 4; ++hh) {
      int r = (hh - g) & 3;
#pragma unroll
      for (int j = 0; j < 7; ++j) acc += w[r][j] * orbs[s][hh * 7 + j];
    }
    h1[(size_t)(b0 + s) * KDIM + g * HID + i] = f2bf(fmaxf(acc, 0.f));
  }
}

// ---------- bf16 MFMA GEMM vs block-circulant weights, bias fused, f32 out ----------
// C[m][n] = bias[n & nmask] + sum_k A[m][k] * Bw[((k>>11)-(n>>n_shift))&3][n&nmask][k&2047]
#define BM 128
#define BN 128
#define BK 64

__global__ __launch_bounds__(256) void gemm_c4(const unsigned short* __restrict__ A,
                                               const unsigned short* __restrict__ Bw,
                                               const float* __restrict__ bias,
                                               float* __restrict__ C,
                                               int N, int n_shift, int nmask, size_t blk_stride) {
  // Fragment-ordered LDS: [half h][mi][ks][lane][8 elems] -> flat idx ((h*4+mi)*2+ks)*512 + lane*8
  __shared__ __align__(16) unsigned short As[8192];
  __shared__ __align__(16) unsigned short Bs[8192];
  int tid = threadIdx.x;
  int wave = tid >> 6;
  int lane = tid & 63;
  int lane15 = lane & 15;
  int lane4 = lane >> 4;
  int m0 = blockIdx.y * BM;
  int n0 = blockIdx.x * BN;
  int g = n0 >> n_shift;
  int n_in_g = n0 & nmask;

  // Staging plan: 16 groups of 1024B per tile; wave w stages groups w*4..w*4+3.
  // group gidx -> (h = gidx>>3, mi = (gidx>>1)&3, ks = gidx&1); within group lane l holds
  // A[m0 + h*64 + mi*16 + (l&15)][k0 + ks*32 + (l>>4)*8 .. +8]  (exactly one MFMA A-frag).
  const unsigned short* Aga[4];
  const unsigned short* Bga[4];
  int ldsOff[4];
#pragma unroll
  for (int j = 0; j < 4; ++j) {
    int gidx = wave * 4 + j;
    int h = gidx >> 3, mi = (gidx >> 1) & 3, ks = gidx & 1;
    int rowOff = h * 64 + mi * 16 + lane15;
    int colOff = ks * 32 + lane4 * 8;
    Aga[j] = A + (size_t)(m0 + rowOff) * KDIM + colOff;
    Bga[j] = Bw + (size_t)(n_in_g + rowOff) * HID + colOff;
    ldsOff[j] = gidx * 1024;  // bytes
  }

  int hA = wave >> 1;  // A half (rows wm = hA*64)
  int hB = wave & 1;   // B half (cols wn = hB*64)
  const unsigned short* Asw = As + hA * 4096;
  const unsigned short* Bsw = Bs + hB * 4096;

  const floatx4 fz = {0.f, 0.f, 0.f, 0.f};
  floatx4 acc[4][4];
#pragma unroll
  for (int a = 0; a < 4; ++a)
#pragma unroll
    for (int b = 0; b < 4; ++b) acc[a][b] = fz;

  for (int k0 = 0; k0 < KDIM; k0 += BK) {
    int blk = ((k0 >> 11) - g) & 3;
    size_t bOff = (size_t)blk * blk_stride + (k0 & (HID - 1));
#pragma unroll
    for (int j = 0; j < 4; ++j)
      __builtin_amdgcn_global_load_lds(
          (const __attribute__((address_space(1))) void*)(Aga[j] + k0),
          (__attribute__((address_space(3))) void*)((char*)As + ldsOff[j]),
          16, 0, 0);
#pragma unroll
    for (int j = 0; j < 4; ++j)
      __builtin_amdgcn_global_load_lds(
          (const __attribute__((address_space(1))) void*)(Bga[j] + bOff),
          (__attribute__((address_space(3))) void*)((char*)Bs + ldsOff[j]),
          16, 0, 0);
    __syncthreads();
#pragma unroll
    for (int ks = 0; ks < 2; ++ks) {
      bf16x8 af[4], bfr[4];
#pragma unroll
      for (int mi = 0; mi < 4; ++mi)
        af[mi] = *(const bf16x8*)&Asw[(mi * 2 + ks) * 512 + lane * 8];
#pragma unroll
      for (int ni = 0; ni < 4; ++ni)
        bfr[ni] = *(const bf16x8*)&Bsw[(ni * 2 + ks) * 512 + lane * 8];
#pragma unroll
      for (int mi = 0; mi < 4; ++mi)
#pragma unroll
        for (int ni = 0; ni < 4; ++ni)
          acc[mi][ni] = __builtin_amdgcn_mfma_f32_16x16x32_bf16(af[mi], bfr[ni], acc[mi][ni], 0, 0, 0);
    }
    __syncthreads();
  }

  // epilogue: C/D layout col=lane&15, row=(lane>>4)*4+r
  int wm = hA * 64, wn = hB * 64;
#pragma unroll
  for (int ni = 0; ni < 4; ++ni) {
    int col = n0 + wn + ni * 16 + lane15;
    float bv = bias[col & nmask];
#pragma unroll
    for (int mi = 0; mi < 4; ++mi) {
      int row = m0 + wm + mi * 16 + lane4 * 4;
#pragma unroll
      for (int r = 0; r < 4; ++r)
        C[(size_t)(row + r) * N + col] = acc[mi][ni][r] + bv;
    }
  }
}

// ---------- LayerNorm(+b2 already fused in GEMM) + relu -> h2 bf16 (in-place over h1c) ----------
__global__ __launch_bounds__(256) void ln_relu_kernel(const float* __restrict__ C2,
                                                      const float* __restrict__ ln_g,
                                                      const float* __restrict__ ln_b,
                                                      unsigned short* __restrict__ h2) {
  int t = threadIdx.x;
  size_t base = (size_t)blockIdx.x * HID;
  const float4* p = (const float4*)(C2 + base);
  float4 x0 = p[t];
  float4 x1 = p[256 + t];
  float s  = x0.x + x0.y + x0.z + x0.w + x1.x + x1.y + x1.z + x1.w;
  float sq = x0.x * x0.x + x0.y * x0.y + x0.z * x0.z + x0.w * x0.w +
             x1.x * x1.x + x1.y * x1.y + x1.z * x1.z + x1.w * x1.w;
#pragma unroll
  for (int off = 32; off > 0; off >>= 1) {
    s  += __shfl_down(s, off, 64);
    sq += __shfl_down(sq, off, 64);
  }
  __shared__ float rs[4], rq[4];
  int w = t >> 6, l = t & 63;
  if (l == 0) { rs[w] = s; rq[w] = sq; }
  __syncthreads();
  s  = rs[0] + rs[1] + rs[2] + rs[3];
  sq = rq[0] + rq[1] + rq[2] + rq[3];
  float mean = s * (1.f / HID);
  float var  = sq * (1.f / HID) - mean * mean;
  float rstd = rsqrtf(var + 1e-5f);
  const float4* gp = (const float4*)ln_g;
  const float4* bp = (const float4*)ln_b;
  float4 g0 = gp[t], g1 = gp[256 + t];
  float4 b0 = bp[t], b1 = bp[256 + t];
  ushort4 o0, o1;
  o0.x = f2bf(fmaxf((x0.x - mean) * rstd * g0.x + b0.x, 0.f));
  o0.y = f2bf(fmaxf((x0.y - mean) * rstd * g0.y + b0.y, 0.f));
  o0.z = f2bf(fmaxf((x0.z - mean) * rstd * g0.z + b0.z, 0.f));
  o0.w = f2bf(fmaxf((x0.w - mean) * rstd * g0.w + b0.w, 0.f));
  o1.x = f2bf(fmaxf((x1.x - mean) * rstd * g1.x + b1.x, 0.f));
  o1.y = f2bf(fmaxf((x1.y - mean) * rstd * g1.y + b1.y, 0.f));
  o1.z = f2bf(fmaxf((x1.z - mean) * rstd * g1.z + b1.z, 0.f));
  o1.w = f2bf(fmaxf((x1.w - mean) * rstd * g1.w + b1.w, 0.f));
  ((ushort4*)(h2 + base))[t] = o0;
  ((ushort4*)(h2 + base))[256 + t] = o1;
}

extern "C" void kernel_launch(void* const* d_in, const int* in_sizes, int n_in,
                              void* d_out, int out_size, void* d_ws, size_t ws_size,
                              hipStream_t stream) {
  const float* ins = (const float*)d_in[0];
  const float* w1  = (const float*)d_in[1];
  const float* b1  = (const float*)d_in[2];
  const float* w2  = (const float*)d_in[3];
  const float* b2  = (const float*)d_in[4];
  const float* w3  = (const float*)d_in[5];
  const float* b3  = (const float*)d_in[6];
  const float* lng = (const float*)d_in[7];
  const float* lnb = (const float*)d_in[8];
  float* out = (float*)d_out;
  char* ws = (char*)d_ws;

  // Persistent weights at base of ws: w2bf 33,554,432 B + w3bf 8,388,608 B.
  const size_t W2B = 33554432ull, W3B = 8388608ull;
  unsigned short* w2bf = (unsigned short*)(ws);
  unsigned short* w3bf = (unsigned short*)(ws + W2B);
  char* chunk_base = ws + W2B + W3B;

  // Pick smallest chunk count P (biggest chunks) whose scratch fits ws_size.
  // Per chunk: h1c bf16 Mc*8192*2  +  C2c f32 Mc*8192*4.
  static const int Pcand[10] = {1, 2, 4, 5, 8, 10, 16, 20, 40, 80};
  int P = 80;
  for (int pi = 0; pi < 10; ++pi) {
    size_t mc = (size_t)MROWS / Pcand[pi];
    size_t need = W2B + W3B + mc * KDIM * 2 + mc * KDIM * 4 + 256;
    if (need <= ws_size) { P = Pcand[pi]; break; }
  }
  const int Mc = MROWS / P;
  unsigned short* h1c = (unsigned short*)chunk_base;                       // Mc x 8192 bf16
  float*          C2c = (float*)(chunk_base + (size_t)Mc * KDIM * 2);     // Mc x 8192 f32

  cvt_bf16_kernel<<<16384, 256, 0, stream>>>(w2, w2bf, 4194304);
  cvt_bf16_kernel<<<4096, 256, 0, stream>>>(w3, w3bf, 1048576);

  for (int c = 0; c < P; ++c) {
    int row0 = c * Mc;
    layer1_kernel<<<dim3(Mc / 32, 32), 256, 0, stream>>>(ins, w1, b1, h1c, row0);
    // L2: M=Mc, N=8192, K=8192; bias b2 fused (pre-LN)
    gemm_c4<<<dim3(64, Mc / 128), 256, 0, stream>>>(h1c, w2bf, b2, C2c, 8192, 11, 2047,
                                                    (size_t)HID * HID);
    ln_relu_kernel<<<Mc * 4, 256, 0, stream>>>(C2c, lng, lnb, h1c);
    // L3: M=Mc, N=2048, K=8192; bias b3 fused
    gemm_c4<<<dim3(16, Mc / 128), 256, 0, stream>>>(h1c, w3bf, b3, out + (size_t)row0 * 2048,
                                                    2048, 9, 511, (size_t)512 * HID);
  }
}

// Round 4
// 2418.525 us; speedup vs baseline: 1.4381x; 1.4381x over previous
//
#include <hip/hip_runtime.h>
#include <stdint.h>

// RotEncoderMLP: orbit-stack -> c4conv(7->2048)+relu -> c4conv(2048->2048)+LN+relu -> c4conv(2048->512)
// All c4convs are GEMMs vs block-circulant weights: Bt[(g,i)][(h,j)] = w[(h-g)&3][i][j].
// L2/L3: bf16 MFMA GEMM, 128x128 tile, BK=64, global_load_lds w=16.
// R4: XOR-swizzled row-major LDS tile. Staging keeps R2's 8x128B contiguous segments per
// instruction (R3's fragment-order staging halved segment size -> 23% slower memory path);
// chunk c of row r lives at physical chunk c^(r&7), implemented by permuting per-lane SOURCE
// columns. Fragment ds_read_b128 XORs the chunk likewise -> 2 lanes/bank-group = conflict-free
// (R2 had 2.5e8 conflict cycles from 16-way aliasing; R3 proved swizzle-free layout costs more
// in VMEM granularity than it saves in LDS).

#define HID 2048
#define KDIM 8192
#define MROWS 10240

typedef float floatx4 __attribute__((ext_vector_type(4)));
typedef __bf16 bf16x8 __attribute__((ext_vector_type(8)));

__device__ __forceinline__ unsigned short f2bf(float f) {
  union { float f; unsigned int u; } v; v.f = f;
  unsigned int r = v.u + 0x7fffu + ((v.u >> 16) & 1u);  // RNE
  return (unsigned short)(r >> 16);
}

// ---------- f32 -> bf16 weight convert ----------
__global__ __launch_bounds__(256) void cvt_bf16_kernel(const float* __restrict__ s,
                                                       unsigned short* __restrict__ d, int n4) {
  int i = blockIdx.x * 256 + threadIdx.x;
  if (i >= n4) return;
  float4 v = ((const float4*)s)[i];
  ushort4 o;
  o.x = f2bf(v.x); o.y = f2bf(v.y); o.z = f2bf(v.z); o.w = f2bf(v.w);
  ((ushort4*)d)[i] = o;
}

// ---------- orbit-stack + layer1 + relu -> h1 bf16 (chunk-local rows x 8192; col = g*2048+i) ----------
__global__ __launch_bounds__(256) void layer1_kernel(const float* __restrict__ ins,
                                                     const float* __restrict__ w1,
                                                     const float* __restrict__ b1,
                                                     unsigned short* __restrict__ h1,
                                                     int row0) {
  __shared__ float orbs[32][28];
  int t = threadIdx.x;
  int b0 = blockIdx.x * 32;            // chunk-local
  int g = blockIdx.y >> 3;
  int i = (blockIdx.y & 7) * 256 + t;
  if (t < 32) {
    const float* x = ins + (size_t)(row0 + b0 + t) * 25;
    float v[25];
#pragma unroll
    for (int p = 0; p < 25; ++p) v[p] = x[p];
    float* o = orbs[t];
    o[0] = v[12]; o[7] = v[12]; o[14] = v[12]; o[21] = v[12];  // center, all 4 rotations
#pragma unroll
    for (int r = 0; r < 2; ++r)
#pragma unroll
      for (int c = 0; c < 3; ++c) {
        int m = 1 + r * 3 + c;
        o[m]      = v[r * 5 + c];              // rot^0: x[r][c]
        o[7 + m]  = v[c * 5 + (4 - r)];        // rot^1: x[c][4-r]
        o[14 + m] = v[(4 - r) * 5 + (4 - c)];  // rot^2
        o[21 + m] = v[(4 - c) * 5 + r];        // rot^3
      }
  }
  __syncthreads();
  float w[4][7];
#pragma unroll
  for (int r = 0; r < 4; ++r)
#pragma unroll
    for (int j = 0; j < 7; ++j) w[r][j] = w1[(r * HID + i) * 7 + j];
  float bias = b1[i];
  for (int s = 0; s < 32; ++s) {
    float acc = bias;
#pragma unroll
    for (int hh = 0; hh < 4; ++hh) {
      int r = (hh - g) & 3;
#pragma unroll
      for (int j = 0; j < 7; ++j) acc += w[r][j] * orbs[s][hh * 7 + j];
    }
    h1[(size_t)(b0 + s) * KDIM + g * HID + i] = f2bf(fmaxf(acc, 0.f));
  }
}

// ---------- bf16 MFMA GEMM vs block-circulant weights, bias fused, f32 out ----------
// C[m][n] = bias[n & nmask] + sum_k A[m][k] * Bw[((k>>11)-(n>>n_shift))&3][n&nmask][k&2047]
#define BM 128
#define BN 128
#define BK 64

__global__ __launch_bounds__(256) void gemm_c4(const unsigned short* __restrict__ A,
                                               const unsigned short* __restrict__ Bw,
                                               const float* __restrict__ bias,
                                               float* __restrict__ C,
                                               int N, int n_shift, int nmask, size_t blk_stride) {
  // Row-major tile (row = 64 elems = 8 chunks of 16B), XOR-swizzled: chunk c of row r is at
  // physical chunk c^(r&7). Staging lane l (per 8-row group) sources chunk (l&7)^(l>>3) of
  // row (l>>3) -> per-row union is the full contiguous 128B segment.
  __shared__ __align__(16) unsigned short As[BM * BK];
  __shared__ __align__(16) unsigned short Bs[BN * BK];
  int tid = threadIdx.x;
  int wave = tid >> 6;
  int lane = tid & 63;
  int lane15 = lane & 15;
  int lane4 = lane >> 4;
  int m0 = blockIdx.y * BM;
  int n0 = blockIdx.x * BN;
  int g = n0 >> n_shift;
  int n_in_g = n0 & nmask;

  int srow = wave * 8 + (lane >> 3);                 // staging row (per 32-row quarter q)
  int scol = ((lane & 7) ^ (lane >> 3)) * 8;         // swizzled source chunk

  const unsigned short* Ag  = A + (size_t)(m0 + srow) * KDIM + scol;
  const unsigned short* Bg0 = Bw + (size_t)(n_in_g + srow) * HID + scol;

  int wm = (wave >> 1) * 64;
  int wn = (wave & 1) * 64;

  const floatx4 fz = {0.f, 0.f, 0.f, 0.f};
  floatx4 acc[4][4];
#pragma unroll
  for (int a = 0; a < 4; ++a)
#pragma unroll
    for (int b = 0; b < 4; ++b) acc[a][b] = fz;

  for (int k0 = 0; k0 < KDIM; k0 += BK) {
    int blk = ((k0 >> 11) - g) & 3;
    const unsigned short* Agk = Ag + k0;
    const unsigned short* Bgk = Bg0 + (size_t)blk * blk_stride + (k0 & (HID - 1));
#pragma unroll
    for (int q = 0; q < 4; ++q)
      __builtin_amdgcn_global_load_lds(
          (const __attribute__((address_space(1))) void*)(Agk + (size_t)q * 32 * KDIM),
          (__attribute__((address_space(3))) void*)((char*)As + q * 4096 + wave * 1024),
          16, 0, 0);
#pragma unroll
    for (int q = 0; q < 4; ++q)
      __builtin_amdgcn_global_load_lds(
          (const __attribute__((address_space(1))) void*)(Bgk + (size_t)q * 32 * HID),
          (__attribute__((address_space(3))) void*)((char*)Bs + q * 4096 + wave * 1024),
          16, 0, 0);
    __syncthreads();
#pragma unroll
    for (int ks = 0; ks < 2; ++ks) {
      // fragment (row, logical chunk ks*4+lane4) -> physical chunk ^(row&7); row&7 == lane15&7
      int chA = ((ks * 4 + lane4) ^ (lane15 & 7)) * 8;
      bf16x8 af[4], bfr[4];
#pragma unroll
      for (int mi = 0; mi < 4; ++mi)
        af[mi] = *(const bf16x8*)&As[(wm + mi * 16 + lane15) * BK + chA];
#pragma unroll
      for (int ni = 0; ni < 4; ++ni)
        bfr[ni] = *(const bf16x8*)&Bs[(wn + ni * 16 + lane15) * BK + chA];
#pragma unroll
      for (int mi = 0; mi < 4; ++mi)
#pragma unroll
        for (int ni = 0; ni < 4; ++ni)
          acc[mi][ni] = __builtin_amdgcn_mfma_f32_16x16x32_bf16(af[mi], bfr[ni], acc[mi][ni], 0, 0, 0);
    }
    __syncthreads();
  }

  // epilogue: C/D layout col=lane&15, row=(lane>>4)*4+r
#pragma unroll
  for (int ni = 0; ni < 4; ++ni) {
    int col = n0 + wn + ni * 16 + lane15;
    float bv = bias[col & nmask];
#pragma unroll
    for (int mi = 0; mi < 4; ++mi) {
      int row = m0 + wm + mi * 16 + lane4 * 4;
#pragma unroll
      for (int r = 0; r < 4; ++r)
        C[(size_t)(row + r) * N + col] = acc[mi][ni][r] + bv;
    }
  }
}

// ---------- LayerNorm(+b2 already fused in GEMM) + relu -> h2 bf16 (in-place over h1c) ----------
__global__ __launch_bounds__(256) void ln_relu_kernel(const float* __restrict__ C2,
                                                      const float* __restrict__ ln_g,
                                                      const float* __restrict__ ln_b,
                                                      unsigned short* __restrict__ h2) {
  int t = threadIdx.x;
  size_t base = (size_t)blockIdx.x * HID;
  const float4* p = (const float4*)(C2 + base);
  float4 x0 = p[t];
  float4 x1 = p[256 + t];
  float s  = x0.x + x0.y + x0.z + x0.w + x1.x + x1.y + x1.z + x1.w;
  float sq = x0.x * x0.x + x0.y * x0.y + x0.z * x0.z + x0.w * x0.w +
             x1.x * x1.x + x1.y * x1.y + x1.z * x1.z + x1.w * x1.w;
#pragma unroll
  for (int off = 32; off > 0; off >>= 1) {
    s  += __shfl_down(s, off, 64);
    sq += __shfl_down(sq, off, 64);
  }
  __shared__ float rs[4], rq[4];
  int w = t >> 6, l = t & 63;
  if (l == 0) { rs[w] = s; rq[w] = sq; }
  __syncthreads();
  s  = rs[0] + rs[1] + rs[2] + rs[3];
  sq = rq[0] + rq[1] + rq[2] + rq[3];
  float mean = s * (1.f / HID);
  float var  = sq * (1.f / HID) - mean * mean;
  float rstd = rsqrtf(var + 1e-5f);
  const float4* gp = (const float4*)ln_g;
  const float4* bp = (const float4*)ln_b;
  float4 g0 = gp[t], g1 = gp[256 + t];
  float4 b0 = bp[t], b1 = bp[256 + t];
  ushort4 o0, o1;
  o0.x = f2bf(fmaxf((x0.x - mean) * rstd * g0.x + b0.x, 0.f));
  o0.y = f2bf(fmaxf((x0.y - mean) * rstd * g0.y + b0.y, 0.f));
  o0.z = f2bf(fmaxf((x0.z - mean) * rstd * g0.z + b0.z, 0.f));
  o0.w = f2bf(fmaxf((x0.w - mean) * rstd * g0.w + b0.w, 0.f));
  o1.x = f2bf(fmaxf((x1.x - mean) * rstd * g1.x + b1.x, 0.f));
  o1.y = f2bf(fmaxf((x1.y - mean) * rstd * g1.y + b1.y, 0.f));
  o1.z = f2bf(fmaxf((x1.z - mean) * rstd * g1.z + b1.z, 0.f));
  o1.w = f2bf(fmaxf((x1.w - mean) * rstd * g1.w + b1.w, 0.f));
  ((ushort4*)(h2 + base))[t] = o0;
  ((ushort4*)(h2 + base))[256 + t] = o1;
}

extern "C" void kernel_launch(void* const* d_in, const int* in_sizes, int n_in,
                              void* d_out, int out_size, void* d_ws, size_t ws_size,
                              hipStream_t stream) {
  const float* ins = (const float*)d_in[0];
  const float* w1  = (const float*)d_in[1];
  const float* b1  = (const float*)d_in[2];
  const float* w2  = (const float*)d_in[3];
  const float* b2  = (const float*)d_in[4];
  const float* w3  = (const float*)d_in[5];
  const float* b3  = (const float*)d_in[6];
  const float* lng = (const float*)d_in[7];
  const float* lnb = (const float*)d_in[8];
  float* out = (float*)d_out;
  char* ws = (char*)d_ws;

  // Persistent weights at base of ws: w2bf 33,554,432 B + w3bf 8,388,608 B.
  const size_t W2B = 33554432ull, W3B = 8388608ull;
  unsigned short* w2bf = (unsigned short*)(ws);
  unsigned short* w3bf = (unsigned short*)(ws + W2B);
  char* chunk_base = ws + W2B + W3B;

  // Pick smallest chunk count P (biggest chunks) whose scratch fits ws_size.
  // Per chunk: h1c bf16 Mc*8192*2  +  C2c f32 Mc*8192*4.
  static const int Pcand[10] = {1, 2, 4, 5, 8, 10, 16, 20, 40, 80};
  int P = 80;
  for (int pi = 0; pi < 10; ++pi) {
    size_t mc = (size_t)MROWS / Pcand[pi];
    size_t need = W2B + W3B + mc * KDIM * 2 + mc * KDIM * 4 + 256;
    if (need <= ws_size) { P = Pcand[pi]; break; }
  }
  const int Mc = MROWS / P;
  unsigned short* h1c = (unsigned short*)chunk_base;                       // Mc x 8192 bf16
  float*          C2c = (float*)(chunk_base + (size_t)Mc * KDIM * 2);     // Mc x 8192 f32

  cvt_bf16_kernel<<<16384, 256, 0, stream>>>(w2, w2bf, 4194304);
  cvt_bf16_kernel<<<4096, 256, 0, stream>>>(w3, w3bf, 1048576);

  for (int c = 0; c < P; ++c) {
    int row0 = c * Mc;
    layer1_kernel<<<dim3(Mc / 32, 32), 256, 0, stream>>>(ins, w1, b1, h1c, row0);
    // L2: M=Mc, N=8192, K=8192; bias b2 fused (pre-LN)
    gemm_c4<<<dim3(64, Mc / 128), 256, 0, stream>>>(h1c, w2bf, b2, C2c, 8192, 11, 2047,
                                                    (size_t)HID * HID);
    ln_relu_kernel<<<Mc * 4, 256, 0, stream>>>(C2c, lng, lnb, h1c);
    // L3: M=Mc, N=2048, K=8192; bias b3 fused
    gemm_c4<<<dim3(16, Mc / 128), 256, 0, stream>>>(h1c, w3bf, b3, out + (size_t)row0 * 2048,
                                                    2048, 9, 511, (size_t)512 * HID);
  }
}

// Round 5
// 1197.528 us; speedup vs baseline: 2.9044x; 2.0196x over previous
//
#include <hip/hip_runtime.h>
#include <stdint.h>

// RotEncoderMLP via Z4-spectral (DFT) decomposition of the C4 group convs.
// c4conv is a correlation over Z4 -> diagonalized by 4-pt DFT: per (b,n),
//   x^[0]=x0+x1+x2+x3, x^[2]=x0-x1+x2-x3, x^[1]=ur+i*ui (ur=x0-x2, ui=x3-x1)
//   y^[w] = conj(W^[w]) . x^[w];  V0=Sum Wr, V2=Sum (-1)^r Wr, V1=(W0-W2)+i(W1-W3)
//   y[g] = (1/4)[y^0 + (-1)^g y^2 + 2 Re(y^1 i^g)]
// MACs: 16*HID^2 -> 6*HID^2 (2.67x FLOP cut). GEMM structure = R4 winner
// (128x128 tile, BK=64, global_load_lds w=16, XOR-swizzled LDS, 0 conflicts).
// Three spectral GEMMs per layer merged into one launch via x-tile routing.

#define HID 2048
#define MROWS 10240

typedef float floatx4 __attribute__((ext_vector_type(4)));
typedef __bf16 bf16x8 __attribute__((ext_vector_type(8)));

__device__ __forceinline__ unsigned short f2bf(float f) {
  union { float f; unsigned int u; } v; v.f = f;
  unsigned int r = v.u + 0x7fffu + ((v.u >> 16) & 1u);  // RNE
  return (unsigned short)(r >> 16);
}

// ---------- spectral weight transform: w (4,NO,2048) f32 -> W0s, W2s (NO x 2048 bf16),
// Bc (2*NO x 4096 bf16) = [[Vr, -Vi],[Vi, Vr]] ----------
template <int NO>
__global__ __launch_bounds__(256) void wtrans_kernel(const float* __restrict__ w,
                                                     unsigned short* __restrict__ W0s,
                                                     unsigned short* __restrict__ W2s,
                                                     unsigned short* __restrict__ Bc) {
  int idx = blockIdx.x * 256 + threadIdx.x;       // i * 512 + j4
  int i = idx >> 9, j4 = idx & 511;
  const float4* wp = (const float4*)w;
  float4 w0 = wp[0 * NO * 512 + i * 512 + j4];
  float4 w1 = wp[1 * NO * 512 + i * 512 + j4];
  float4 w2 = wp[2 * NO * 512 + i * 512 + j4];
  float4 w3 = wp[3 * NO * 512 + i * 512 + j4];
  ushort4 s0, s2, vr, vi, nvi;
#define DO(c)                                        \
  s0.c = f2bf(w0.c + w1.c + w2.c + w3.c);            \
  s2.c = f2bf(w0.c - w1.c + w2.c - w3.c);            \
  vr.c = f2bf(w0.c - w2.c);                          \
  vi.c = f2bf(w1.c - w3.c);                          \
  nvi.c = f2bf(-(w1.c - w3.c));
  DO(x) DO(y) DO(z) DO(w)
#undef DO
  ((ushort4*)W0s)[i * 512 + j4] = s0;
  ((ushort4*)W2s)[i * 512 + j4] = s2;
  ((ushort4*)Bc)[i * 1024 + j4] = vr;            // row i:    [Vr | -Vi]
  ((ushort4*)Bc)[i * 1024 + 512 + j4] = nvi;
  ((ushort4*)Bc)[(NO + i) * 1024 + j4] = vi;     // row NO+i: [Vi |  Vr]
  ((ushort4*)Bc)[(NO + i) * 1024 + 512 + j4] = vr;
}

// ---------- orbit-stack + layer1 + relu + forward-DFT -> h1s bf16 (Mc x 8192: [u0|u2|ur|ui]) ----------
__global__ __launch_bounds__(256) void layer1_kernel(const float* __restrict__ ins,
                                                     const float* __restrict__ w1,
                                                     const float* __restrict__ b1,
                                                     unsigned short* __restrict__ h1s,
                                                     int row0) {
  __shared__ float orbs[32][28];
  int t = threadIdx.x;
  int b0 = blockIdx.x * 32;            // chunk-local
  int i = blockIdx.y * 256 + t;
  if (t < 32) {
    const float* x = ins + (size_t)(row0 + b0 + t) * 25;
    float v[25];
#pragma unroll
    for (int p = 0; p < 25; ++p) v[p] = x[p];
    float* o = orbs[t];
    o[0] = v[12]; o[7] = v[12]; o[14] = v[12]; o[21] = v[12];
#pragma unroll
    for (int r = 0; r < 2; ++r)
#pragma unroll
      for (int c = 0; c < 3; ++c) {
        int m = 1 + r * 3 + c;
        o[m]      = v[r * 5 + c];
        o[7 + m]  = v[c * 5 + (4 - r)];
        o[14 + m] = v[(4 - r) * 5 + (4 - c)];
        o[21 + m] = v[(4 - c) * 5 + r];
      }
  }
  __syncthreads();
  float w[4][7];
#pragma unroll
  for (int r = 0; r < 4; ++r)
#pragma unroll
    for (int j = 0; j < 7; ++j) w[r][j] = w1[(r * HID + i) * 7 + j];
  float bias = b1[i];
  for (int s = 0; s < 32; ++s) {
    float a[4] = {bias, bias, bias, bias};
#pragma unroll
    for (int hh = 0; hh < 4; ++hh)
#pragma unroll
      for (int j = 0; j < 7; ++j) {
        float ov = orbs[s][hh * 7 + j];
#pragma unroll
        for (int g = 0; g < 4; ++g) a[g] += w[(hh - g) & 3][j] * ov;
      }
    float h0 = fmaxf(a[0], 0.f), h1 = fmaxf(a[1], 0.f);
    float h2 = fmaxf(a[2], 0.f), h3 = fmaxf(a[3], 0.f);
    size_t base = (size_t)(b0 + s) * 8192 + i;
    h1s[base]        = f2bf(h0 + h1 + h2 + h3);  // u0
    h1s[base + 2048] = f2bf(h0 - h1 + h2 - h3);  // u2
    h1s[base + 4096] = f2bf(h0 - h2);            // ur
    h1s[base + 6144] = f2bf(h3 - h1);            // ui
  }
}

// ---------- bf16 MFMA GEMM, 3 spectral segments merged via x-tile routing ----------
// seg a (bx<s1):  B=B0, K=2048, aoff=0,    coff=0     (y^0 = u0 @ V0^T)
// seg b (bx<s2):  B=B1, K=2048, aoff=2048, coff=N0    (y^2 = u2 @ V2^T)
// seg c (else):   B=B2, K=4096, aoff=4096, coff=2*N0  ([yr|yi] = [ur|ui] @ Bc^T)
#define BM 128
#define BN 128
#define BK 64

__global__ __launch_bounds__(256) void gemm_spec(const unsigned short* __restrict__ A,
                                                 const unsigned short* __restrict__ B0,
                                                 const unsigned short* __restrict__ B1,
                                                 const unsigned short* __restrict__ B2,
                                                 float* __restrict__ C,
                                                 int s1, int s2, int N0, int ldc) {
  __shared__ __align__(16) unsigned short As[BM * BK];
  __shared__ __align__(16) unsigned short Bs[BN * BK];
  int tid = threadIdx.x;
  int wave = tid >> 6;
  int lane = tid & 63;
  int lane15 = lane & 15;
  int lane4 = lane >> 4;
  int m0 = blockIdx.y * BM;

  int bx = blockIdx.x;
  const unsigned short* Bp;
  int K, aoff, coff, nloc;
  if (bx < s1)      { Bp = B0; K = 2048; aoff = 0;    coff = 0;      nloc = bx * BN; }
  else if (bx < s2) { Bp = B1; K = 2048; aoff = 2048; coff = N0;     nloc = (bx - s1) * BN; }
  else              { Bp = B2; K = 4096; aoff = 4096; coff = 2 * N0; nloc = (bx - s2) * BN; }
  int ldb = K;

  int srow = wave * 8 + (lane >> 3);                 // staging row (per 32-row quarter q)
  int scol = ((lane & 7) ^ (lane >> 3)) * 8;         // XOR-swizzled source chunk

  const unsigned short* Ag = A + (size_t)(m0 + srow) * 8192 + aoff + scol;
  const unsigned short* Bg = Bp + (size_t)(nloc + srow) * ldb + scol;

  int wm = (wave >> 1) * 64;
  int wn = (wave & 1) * 64;

  const floatx4 fz = {0.f, 0.f, 0.f, 0.f};
  floatx4 acc[4][4];
#pragma unroll
  for (int a = 0; a < 4; ++a)
#pragma unroll
    for (int b = 0; b < 4; ++b) acc[a][b] = fz;

  for (int k0 = 0; k0 < K; k0 += BK) {
#pragma unroll
    for (int q = 0; q < 4; ++q)
      __builtin_amdgcn_global_load_lds(
          (const __attribute__((address_space(1))) void*)(Ag + k0 + (size_t)q * 32 * 8192),
          (__attribute__((address_space(3))) void*)((char*)As + q * 4096 + wave * 1024),
          16, 0, 0);
#pragma unroll
    for (int q = 0; q < 4; ++q)
      __builtin_amdgcn_global_load_lds(
          (const __attribute__((address_space(1))) void*)(Bg + k0 + (size_t)q * 32 * ldb),
          (__attribute__((address_space(3))) void*)((char*)Bs + q * 4096 + wave * 1024),
          16, 0, 0);
    __syncthreads();
#pragma unroll
    for (int ks = 0; ks < 2; ++ks) {
      int chA = ((ks * 4 + lane4) ^ (lane15 & 7)) * 8;
      bf16x8 af[4], bfr[4];
#pragma unroll
      for (int mi = 0; mi < 4; ++mi)
        af[mi] = *(const bf16x8*)&As[(wm + mi * 16 + lane15) * BK + chA];
#pragma unroll
      for (int ni = 0; ni < 4; ++ni)
        bfr[ni] = *(const bf16x8*)&Bs[(wn + ni * 16 + lane15) * BK + chA];
#pragma unroll
      for (int mi = 0; mi < 4; ++mi)
#pragma unroll
        for (int ni = 0; ni < 4; ++ni)
          acc[mi][ni] = __builtin_amdgcn_mfma_f32_16x16x32_bf16(af[mi], bfr[ni], acc[mi][ni], 0, 0, 0);
    }
    __syncthreads();
  }

  // epilogue: C/D layout col=lane&15, row=(lane>>4)*4+r
#pragma unroll
  for (int ni = 0; ni < 4; ++ni) {
    int col = coff + nloc + wn + ni * 16 + lane15;
#pragma unroll
    for (int mi = 0; mi < 4; ++mi) {
      int row = m0 + wm + mi * 16 + lane4 * 4;
#pragma unroll
      for (int r = 0; r < 4; ++r)
        C[(size_t)(row + r) * ldc + col] = acc[mi][ni][r];
    }
  }
}

// ---------- inverse-DFT (+b2, /4) -> 4x LayerNorm -> relu -> forward-DFT -> h1s bf16 ----------
__global__ __launch_bounds__(256) void ln_spec_kernel(const float* __restrict__ C2,
                                                      const float* __restrict__ b2,
                                                      const float* __restrict__ ln_g,
                                                      const float* __restrict__ ln_b,
                                                      unsigned short* __restrict__ h1s) {
  int t = threadIdx.x;
  size_t base = (size_t)blockIdx.x * 8192;
  const float4* p = (const float4*)(C2 + base);   // planes: v0 | v2 | vr | vi (512 float4 each)
  const float4* bp2 = (const float4*)b2;
  float4 y[4][2];
  float s[4] = {0, 0, 0, 0}, q[4] = {0, 0, 0, 0};
#pragma unroll
  for (int hl = 0; hl < 2; ++hl) {
    int j = hl * 256 + t;
    float4 v0 = p[j], v2 = p[512 + j], vr = p[1024 + j], vi = p[1536 + j];
    float4 bb = bp2[j];
#define DO(c)                                                   \
  {                                                             \
    float e0 = 0.25f * (v0.c + v2.c + 2.f * vr.c) + bb.c;       \
    float e1 = 0.25f * (v0.c - v2.c - 2.f * vi.c) + bb.c;       \
    float e2 = 0.25f * (v0.c + v2.c - 2.f * vr.c) + bb.c;       \
    float e3 = 0.25f * (v0.c - v2.c + 2.f * vi.c) + bb.c;       \
    y[0][hl].c = e0; y[1][hl].c = e1; y[2][hl].c = e2; y[3][hl].c = e3; \
    s[0] += e0; q[0] += e0 * e0; s[1] += e1; q[1] += e1 * e1;   \
    s[2] += e2; q[2] += e2 * e2; s[3] += e3; q[3] += e3 * e3;   \
  }
    DO(x) DO(y) DO(z) DO(w)
#undef DO
  }
#pragma unroll
  for (int off = 32; off > 0; off >>= 1)
#pragma unroll
    for (int g = 0; g < 4; ++g) {
      s[g] += __shfl_down(s[g], off, 64);
      q[g] += __shfl_down(q[g], off, 64);
    }
  __shared__ float rs[4][4], rq[4][4];
  int w = t >> 6, l = t & 63;
  if (l == 0)
#pragma unroll
    for (int g = 0; g < 4; ++g) { rs[w][g] = s[g]; rq[w][g] = q[g]; }
  __syncthreads();
  float mean[4], rstd[4];
#pragma unroll
  for (int g = 0; g < 4; ++g) {
    float ss = rs[0][g] + rs[1][g] + rs[2][g] + rs[3][g];
    float qq = rq[0][g] + rq[1][g] + rq[2][g] + rq[3][g];
    mean[g] = ss * (1.f / HID);
    float var = qq * (1.f / HID) - mean[g] * mean[g];
    rstd[g] = rsqrtf(var + 1e-5f);
  }
  const float4* gp = (const float4*)ln_g;
  const float4* lbp = (const float4*)ln_b;
#pragma unroll
  for (int hl = 0; hl < 2; ++hl) {
    int j = hl * 256 + t;
    float4 gg = gp[j], lb = lbp[j];
    ushort4 o[4];
#define DO(c)                                                               \
  {                                                                         \
    float h0 = fmaxf((y[0][hl].c - mean[0]) * rstd[0] * gg.c + lb.c, 0.f);  \
    float h1 = fmaxf((y[1][hl].c - mean[1]) * rstd[1] * gg.c + lb.c, 0.f);  \
    float h2 = fmaxf((y[2][hl].c - mean[2]) * rstd[2] * gg.c + lb.c, 0.f);  \
    float h3 = fmaxf((y[3][hl].c - mean[3]) * rstd[3] * gg.c + lb.c, 0.f);  \
    o[0].c = f2bf(h0 + h1 + h2 + h3);                                       \
    o[1].c = f2bf(h0 - h1 + h2 - h3);                                       \
    o[2].c = f2bf(h0 - h2);                                                 \
    o[3].c = f2bf(h3 - h1);                                                 \
  }
    DO(x) DO(y) DO(z) DO(w)
#undef DO
    size_t ob = (size_t)blockIdx.x * 8192;
#pragma unroll
    for (int pl = 0; pl < 4; ++pl)
      ((ushort4*)(h1s + ob + pl * 2048))[j] = o[pl];
  }
}

// ---------- final inverse-DFT (+b3, /4): z (Mc x 2048 f32 [z0|z2|zr|zi]) -> out ----------
__global__ __launch_bounds__(256) void out_ep_kernel(const float* __restrict__ Z,
                                                     const float* __restrict__ b3,
                                                     float* __restrict__ out) {
  int e = blockIdx.x * 256 + threadIdx.x;
  int row = e >> 9, i = e & 511;
  size_t base = (size_t)row * 2048;
  float z0 = Z[base + i], z2 = Z[base + 512 + i];
  float zr = Z[base + 1024 + i], zi = Z[base + 1536 + i];
  float bv = b3[i];
  out[base + i]        = 0.25f * (z0 + z2 + 2.f * zr) + bv;
  out[base + 512 + i]  = 0.25f * (z0 - z2 - 2.f * zi) + bv;
  out[base + 1024 + i] = 0.25f * (z0 + z2 - 2.f * zr) + bv;
  out[base + 1536 + i] = 0.25f * (z0 - z2 + 2.f * zi) + bv;
}

extern "C" void kernel_launch(void* const* d_in, const int* in_sizes, int n_in,
                              void* d_out, int out_size, void* d_ws, size_t ws_size,
                              hipStream_t stream) {
  const float* ins = (const float*)d_in[0];
  const float* w1  = (const float*)d_in[1];
  const float* b1  = (const float*)d_in[2];
  const float* w2  = (const float*)d_in[3];
  const float* b2  = (const float*)d_in[4];
  const float* w3  = (const float*)d_in[5];
  const float* b3  = (const float*)d_in[6];
  const float* lng = (const float*)d_in[7];
  const float* lnb = (const float*)d_in[8];
  float* out = (float*)d_out;
  char* ws = (char*)d_ws;

  // Spectral weights (bf16), persistent at base of ws:
  // W0s2 (2048x2048) | W2s2 | Bc2 (4096x4096) | W0s3 (512x2048) | W2s3 | Bc3 (1024x4096)
  unsigned short* W0s2 = (unsigned short*)ws;
  unsigned short* W2s2 = W0s2 + 4194304;
  unsigned short* Bc2  = W2s2 + 4194304;
  unsigned short* W0s3 = Bc2 + 16777216;
  unsigned short* W2s3 = W0s3 + 1048576;
  unsigned short* Bc3  = W2s3 + 1048576;
  const size_t WT_BYTES = 62914560ull;  // 31,457,280 elems * 2 B
  char* chunk_base = ws + WT_BYTES;

  // Pick smallest chunk count P (biggest chunks) whose scratch fits ws_size.
  // Per chunk: h1s bf16 Mc*8192 + C2 f32 Mc*8192 (z aliases C2's first Mc*2048 f32).
  static const int Pcand[10] = {1, 2, 4, 5, 8, 10, 16, 20, 40, 80};
  int P = 80;
  for (int pi = 0; pi < 10; ++pi) {
    size_t mc = (size_t)MROWS / Pcand[pi];
    size_t need = WT_BYTES + mc * 8192 * 2 + mc * 8192 * 4 + 256;
    if (need <= ws_size) { P = Pcand[pi]; break; }
  }
  const int Mc = MROWS / P;
  unsigned short* h1s = (unsigned short*)chunk_base;                     // Mc x 8192 bf16
  float*          C2  = (float*)(chunk_base + (size_t)Mc * 8192 * 2);    // Mc x 8192 f32
  float*          Z   = C2;                                              // Mc x 2048 f32 (alias)

  wtrans_kernel<2048><<<4096, 256, 0, stream>>>(w2, W0s2, W2s2, Bc2);
  wtrans_kernel<512><<<1024, 256, 0, stream>>>(w3, W0s3, W2s3, Bc3);

  for (int c = 0; c < P; ++c) {
    int row0 = c * Mc;
    layer1_kernel<<<dim3(Mc / 32, 8), 256, 0, stream>>>(ins, w1, b1, h1s, row0);
    // L2 spectral: x-tiles [0,16)=V0 (K=2048), [16,32)=V2, [32,64)=Bc (K=4096)
    gemm_spec<<<dim3(64, Mc / 128), 256, 0, stream>>>(h1s, W0s2, W2s2, Bc2, C2,
                                                      16, 32, 2048, 8192);
    ln_spec_kernel<<<Mc, 256, 0, stream>>>(C2, b2, lng, lnb, h1s);
    // L3 spectral: x-tiles [0,4)=V0', [4,8)=V2', [8,16)=Bc' -> Z (ldc 2048)
    gemm_spec<<<dim3(16, Mc / 128), 256, 0, stream>>>(h1s, W0s3, W2s3, Bc3, Z,
                                                      4, 8, 512, 2048);
    out_ep_kernel<<<Mc * 2, 256, 0, stream>>>(Z, b3, out + (size_t)row0 * 2048);
  }
}

// Round 6
// 1182.411 us; speedup vs baseline: 2.9416x; 1.0128x over previous
//
#include <hip/hip_runtime.h>
#include <stdint.h>

// RotEncoderMLP via Z4-spectral (DFT) decomposition of the C4 group convs.
//   x^[0]=x0+x1+x2+x3, x^[2]=x0-x1+x2-x3, x^[1]=ur+i*ui (ur=x0-x2, ui=x3-x1)
//   y^[w] = conj(W^[w]) . x^[w];  y[g] = (1/4)[y^0 + (-1)^g y^2 + 2 Re(y^1 i^g)]
// MACs: 16*HID^2 -> 6*HID^2. GEMM = R4 winner (128x128, BK=64, global_load_lds w=16,
// XOR-swizzled LDS, 0 conflicts) + R6: panel-swizzled block traversal (concurrent
// window = 8 n-tiles x all M -> small L2/L3 working set; R5 showed 6x HBM overfetch
// with bx-fastest order) and bf16 C2 (pre-LN spectral activations; halves that traffic).

#define HID 2048
#define MROWS 10240

typedef float floatx4 __attribute__((ext_vector_type(4)));
typedef __bf16 bf16x8 __attribute__((ext_vector_type(8)));

__device__ __forceinline__ unsigned short f2bf(float f) {
  union { float f; unsigned int u; } v; v.f = f;
  unsigned int r = v.u + 0x7fffu + ((v.u >> 16) & 1u);  // RNE
  return (unsigned short)(r >> 16);
}
__device__ __forceinline__ float bf2f(unsigned short s) {
  union { unsigned int u; float f; } v; v.u = ((unsigned int)s) << 16;
  return v.f;
}

// ---------- spectral weight transform: w (4,NO,2048) f32 -> W0s, W2s (NO x 2048 bf16),
// Bc (2*NO x 4096 bf16) = [[Vr, -Vi],[Vi, Vr]] ----------
template <int NO>
__global__ __launch_bounds__(256) void wtrans_kernel(const float* __restrict__ w,
                                                     unsigned short* __restrict__ W0s,
                                                     unsigned short* __restrict__ W2s,
                                                     unsigned short* __restrict__ Bc) {
  int idx = blockIdx.x * 256 + threadIdx.x;       // i * 512 + j4
  int i = idx >> 9, j4 = idx & 511;
  const float4* wp = (const float4*)w;
  float4 w0 = wp[0 * NO * 512 + i * 512 + j4];
  float4 w1 = wp[1 * NO * 512 + i * 512 + j4];
  float4 w2 = wp[2 * NO * 512 + i * 512 + j4];
  float4 w3 = wp[3 * NO * 512 + i * 512 + j4];
  ushort4 s0, s2, vr, vi, nvi;
#define DO(c)                                        \
  s0.c = f2bf(w0.c + w1.c + w2.c + w3.c);            \
  s2.c = f2bf(w0.c - w1.c + w2.c - w3.c);            \
  vr.c = f2bf(w0.c - w2.c);                          \
  vi.c = f2bf(w1.c - w3.c);                          \
  nvi.c = f2bf(-(w1.c - w3.c));
  DO(x) DO(y) DO(z) DO(w)
#undef DO
  ((ushort4*)W0s)[i * 512 + j4] = s0;
  ((ushort4*)W2s)[i * 512 + j4] = s2;
  ((ushort4*)Bc)[i * 1024 + j4] = vr;            // row i:    [Vr | -Vi]
  ((ushort4*)Bc)[i * 1024 + 512 + j4] = nvi;
  ((ushort4*)Bc)[(NO + i) * 1024 + j4] = vi;     // row NO+i: [Vi |  Vr]
  ((ushort4*)Bc)[(NO + i) * 1024 + 512 + j4] = vr;
}

// ---------- orbit-stack + layer1 + relu + forward-DFT -> h1s bf16 (Mc x 8192: [u0|u2|ur|ui]) ----------
__global__ __launch_bounds__(256) void layer1_kernel(const float* __restrict__ ins,
                                                     const float* __restrict__ w1,
                                                     const float* __restrict__ b1,
                                                     unsigned short* __restrict__ h1s,
                                                     int row0) {
  __shared__ float orbs[32][28];
  int t = threadIdx.x;
  int b0 = blockIdx.x * 32;            // chunk-local
  int i = blockIdx.y * 256 + t;
  if (t < 32) {
    const float* x = ins + (size_t)(row0 + b0 + t) * 25;
    float v[25];
#pragma unroll
    for (int p = 0; p < 25; ++p) v[p] = x[p];
    float* o = orbs[t];
    o[0] = v[12]; o[7] = v[12]; o[14] = v[12]; o[21] = v[12];
#pragma unroll
    for (int r = 0; r < 2; ++r)
#pragma unroll
      for (int c = 0; c < 3; ++c) {
        int m = 1 + r * 3 + c;
        o[m]      = v[r * 5 + c];
        o[7 + m]  = v[c * 5 + (4 - r)];
        o[14 + m] = v[(4 - r) * 5 + (4 - c)];
        o[21 + m] = v[(4 - c) * 5 + r];
      }
  }
  __syncthreads();
  float w[4][7];
#pragma unroll
  for (int r = 0; r < 4; ++r)
#pragma unroll
    for (int j = 0; j < 7; ++j) w[r][j] = w1[(r * HID + i) * 7 + j];
  float bias = b1[i];
  for (int s = 0; s < 32; ++s) {
    float a[4] = {bias, bias, bias, bias};
#pragma unroll
    for (int hh = 0; hh < 4; ++hh)
#pragma unroll
      for (int j = 0; j < 7; ++j) {
        float ov = orbs[s][hh * 7 + j];
#pragma unroll
        for (int g = 0; g < 4; ++g) a[g] += w[(hh - g) & 3][j] * ov;
      }
    float h0 = fmaxf(a[0], 0.f), h1 = fmaxf(a[1], 0.f);
    float h2 = fmaxf(a[2], 0.f), h3 = fmaxf(a[3], 0.f);
    size_t base = (size_t)(b0 + s) * 8192 + i;
    h1s[base]        = f2bf(h0 + h1 + h2 + h3);  // u0
    h1s[base + 2048] = f2bf(h0 - h1 + h2 - h3);  // u2
    h1s[base + 4096] = f2bf(h0 - h2);            // ur
    h1s[base + 6144] = f2bf(h3 - h1);            // ui
  }
}

// ---------- bf16 MFMA GEMM, 3 spectral segments merged, panel-swizzled traversal ----------
// n-tile nt routing: nt<s1: B0,K=2048,aoff=0; nt<s2: B1,K=2048,aoff=2048; else B2,K=4096,aoff=4096.
// Output: bf16 to Cb (if non-null) else f32 to Cf.
#define BM 128
#define BN 128
#define BK 64
#define PW 8  // panel width in n-tiles

__global__ __launch_bounds__(256) void gemm_spec(const unsigned short* __restrict__ A,
                                                 const unsigned short* __restrict__ B0,
                                                 const unsigned short* __restrict__ B1,
                                                 const unsigned short* __restrict__ B2,
                                                 float* __restrict__ Cf,
                                                 unsigned short* __restrict__ Cb,
                                                 int s1, int s2, int N0, int ldc) {
  __shared__ __align__(16) unsigned short As[BM * BK];
  __shared__ __align__(16) unsigned short Bs[BN * BK];
  int tid = threadIdx.x;
  int wave = tid >> 6;
  int lane = tid & 63;
  int lane15 = lane & 15;
  int lane4 = lane >> 4;

  // panel swizzle: consecutive flat IDs sweep all M-tiles within an 8-wide n-tile panel
  int flat = blockIdx.y * gridDim.x + blockIdx.x;
  int panel = flat / (PW * gridDim.y);
  int rem = flat % (PW * gridDim.y);
  int mt = rem / PW;
  int nt = panel * PW + rem % PW;
  int m0 = mt * BM;

  const unsigned short* Bp;
  int K, aoff, coff, nloc;
  if (nt < s1)      { Bp = B0; K = 2048; aoff = 0;    coff = 0;      nloc = nt * BN; }
  else if (nt < s2) { Bp = B1; K = 2048; aoff = 2048; coff = N0;     nloc = (nt - s1) * BN; }
  else              { Bp = B2; K = 4096; aoff = 4096; coff = 2 * N0; nloc = (nt - s2) * BN; }
  int ldb = K;

  int srow = wave * 8 + (lane >> 3);                 // staging row (per 32-row quarter q)
  int scol = ((lane & 7) ^ (lane >> 3)) * 8;         // XOR-swizzled source chunk

  const unsigned short* Ag = A + (size_t)(m0 + srow) * 8192 + aoff + scol;
  const unsigned short* Bg = Bp + (size_t)(nloc + srow) * ldb + scol;

  int wm = (wave >> 1) * 64;
  int wn = (wave & 1) * 64;

  const floatx4 fz = {0.f, 0.f, 0.f, 0.f};
  floatx4 acc[4][4];
#pragma unroll
  for (int a = 0; a < 4; ++a)
#pragma unroll
    for (int b = 0; b < 4; ++b) acc[a][b] = fz;

  for (int k0 = 0; k0 < K; k0 += BK) {
#pragma unroll
    for (int q = 0; q < 4; ++q)
      __builtin_amdgcn_global_load_lds(
          (const __attribute__((address_space(1))) void*)(Ag + k0 + (size_t)q * 32 * 8192),
          (__attribute__((address_space(3))) void*)((char*)As + q * 4096 + wave * 1024),
          16, 0, 0);
#pragma unroll
    for (int q = 0; q < 4; ++q)
      __builtin_amdgcn_global_load_lds(
          (const __attribute__((address_space(1))) void*)(Bg + k0 + (size_t)q * 32 * ldb),
          (__attribute__((address_space(3))) void*)((char*)Bs + q * 4096 + wave * 1024),
          16, 0, 0);
    __syncthreads();
#pragma unroll
    for (int ks = 0; ks < 2; ++ks) {
      int chA = ((ks * 4 + lane4) ^ (lane15 & 7)) * 8;
      bf16x8 af[4], bfr[4];
#pragma unroll
      for (int mi = 0; mi < 4; ++mi)
        af[mi] = *(const bf16x8*)&As[(wm + mi * 16 + lane15) * BK + chA];
#pragma unroll
      for (int ni = 0; ni < 4; ++ni)
        bfr[ni] = *(const bf16x8*)&Bs[(wn + ni * 16 + lane15) * BK + chA];
#pragma unroll
      for (int mi = 0; mi < 4; ++mi)
#pragma unroll
        for (int ni = 0; ni < 4; ++ni)
          acc[mi][ni] = __builtin_amdgcn_mfma_f32_16x16x32_bf16(af[mi], bfr[ni], acc[mi][ni], 0, 0, 0);
    }
    __syncthreads();
  }

  // epilogue: C/D layout col=lane&15, row=(lane>>4)*4+r
#pragma unroll
  for (int ni = 0; ni < 4; ++ni) {
    int col = coff + nloc + wn + ni * 16 + lane15;
#pragma unroll
    for (int mi = 0; mi < 4; ++mi) {
      int row = m0 + wm + mi * 16 + lane4 * 4;
      if (Cb) {
#pragma unroll
        for (int r = 0; r < 4; ++r)
          Cb[(size_t)(row + r) * ldc + col] = f2bf(acc[mi][ni][r]);
      } else {
#pragma unroll
        for (int r = 0; r < 4; ++r)
          Cf[(size_t)(row + r) * ldc + col] = acc[mi][ni][r];
      }
    }
  }
}

// ---------- inverse-DFT (+b2, /4) -> 4x LayerNorm -> relu -> forward-DFT -> h1s bf16 ----------
__global__ __launch_bounds__(256) void ln_spec_kernel(const unsigned short* __restrict__ C2,
                                                      const float* __restrict__ b2,
                                                      const float* __restrict__ ln_g,
                                                      const float* __restrict__ ln_b,
                                                      unsigned short* __restrict__ h1s) {
  int t = threadIdx.x;
  size_t base = (size_t)blockIdx.x * 8192;
  const ushort4* p = (const ushort4*)(C2 + base);   // planes: v0|v2|vr|vi (512 ushort4 each)
  const float4* bp2 = (const float4*)b2;
  float4 y[4][2];
  float s[4] = {0, 0, 0, 0}, q[4] = {0, 0, 0, 0};
#pragma unroll
  for (int hl = 0; hl < 2; ++hl) {
    int j = hl * 256 + t;
    ushort4 u0 = p[j], u2 = p[512 + j], ur = p[1024 + j], ui = p[1536 + j];
    float4 bb = bp2[j];
#define DO(c)                                                   \
  {                                                             \
    float v0 = bf2f(u0.c), v2 = bf2f(u2.c);                     \
    float vr = bf2f(ur.c), vi = bf2f(ui.c);                     \
    float e0 = 0.25f * (v0 + v2 + 2.f * vr) + bb.c;             \
    float e1 = 0.25f * (v0 - v2 - 2.f * vi) + bb.c;             \
    float e2 = 0.25f * (v0 + v2 - 2.f * vr) + bb.c;             \
    float e3 = 0.25f * (v0 - v2 + 2.f * vi) + bb.c;             \
    y[0][hl].c = e0; y[1][hl].c = e1; y[2][hl].c = e2; y[3][hl].c = e3; \
    s[0] += e0; q[0] += e0 * e0; s[1] += e1; q[1] += e1 * e1;   \
    s[2] += e2; q[2] += e2 * e2; s[3] += e3; q[3] += e3 * e3;   \
  }
    DO(x) DO(y) DO(z) DO(w)
#undef DO
  }
#pragma unroll
  for (int off = 32; off > 0; off >>= 1)
#pragma unroll
    for (int g = 0; g < 4; ++g) {
      s[g] += __shfl_down(s[g], off, 64);
      q[g] += __shfl_down(q[g], off, 64);
    }
  __shared__ float rs[4][4], rq[4][4];
  int w = t >> 6, l = t & 63;
  if (l == 0)
#pragma unroll
    for (int g = 0; g < 4; ++g) { rs[w][g] = s[g]; rq[w][g] = q[g]; }
  __syncthreads();
  float mean[4], rstd[4];
#pragma unroll
  for (int g = 0; g < 4; ++g) {
    float ss = rs[0][g] + rs[1][g] + rs[2][g] + rs[3][g];
    float qq = rq[0][g] + rq[1][g] + rq[2][g] + rq[3][g];
    mean[g] = ss * (1.f / HID);
    float var = qq * (1.f / HID) - mean[g] * mean[g];
    rstd[g] = rsqrtf(var + 1e-5f);
  }
  const float4* gp = (const float4*)ln_g;
  const float4* lbp = (const float4*)ln_b;
#pragma unroll
  for (int hl = 0; hl < 2; ++hl) {
    int j = hl * 256 + t;
    float4 gg = gp[j], lb = lbp[j];
    ushort4 o[4];
#define DO(c)                                                               \
  {                                                                         \
    float h0 = fmaxf((y[0][hl].c - mean[0]) * rstd[0] * gg.c + lb.c, 0.f);  \
    float h1 = fmaxf((y[1][hl].c - mean[1]) * rstd[1] * gg.c + lb.c, 0.f);  \
    float h2 = fmaxf((y[2][hl].c - mean[2]) * rstd[2] * gg.c + lb.c, 0.f);  \
    float h3 = fmaxf((y[3][hl].c - mean[3]) * rstd[3] * gg.c + lb.c, 0.f);  \
    o[0].c = f2bf(h0 + h1 + h2 + h3);                                       \
    o[1].c = f2bf(h0 - h1 + h2 - h3);                                       \
    o[2].c = f2bf(h0 - h2);                                                 \
    o[3].c = f2bf(h3 - h1);                                                 \
  }
    DO(x) DO(y) DO(z) DO(w)
#undef DO
    size_t ob = (size_t)blockIdx.x * 8192;
#pragma unroll
    for (int pl = 0; pl < 4; ++pl)
      ((ushort4*)(h1s + ob + pl * 2048))[j] = o[pl];
  }
}

// ---------- final inverse-DFT (+b3, /4): Z (Mc x 2048 f32 [z0|z2|zr|zi]) -> out ----------
__global__ __launch_bounds__(256) void out_ep_kernel(const float* __restrict__ Z,
                                                     const float* __restrict__ b3,
                                                     float* __restrict__ out) {
  int e = blockIdx.x * 256 + threadIdx.x;
  int row = e >> 9, i = e & 511;
  size_t base = (size_t)row * 2048;
  float z0 = Z[base + i], z2 = Z[base + 512 + i];
  float zr = Z[base + 1024 + i], zi = Z[base + 1536 + i];
  float bv = b3[i];
  out[base + i]        = 0.25f * (z0 + z2 + 2.f * zr) + bv;
  out[base + 512 + i]  = 0.25f * (z0 - z2 - 2.f * zi) + bv;
  out[base + 1024 + i] = 0.25f * (z0 + z2 - 2.f * zr) + bv;
  out[base + 1536 + i] = 0.25f * (z0 - z2 + 2.f * zi) + bv;
}

extern "C" void kernel_launch(void* const* d_in, const int* in_sizes, int n_in,
                              void* d_out, int out_size, void* d_ws, size_t ws_size,
                              hipStream_t stream) {
  const float* ins = (const float*)d_in[0];
  const float* w1  = (const float*)d_in[1];
  const float* b1  = (const float*)d_in[2];
  const float* w2  = (const float*)d_in[3];
  const float* b2  = (const float*)d_in[4];
  const float* w3  = (const float*)d_in[5];
  const float* b3  = (const float*)d_in[6];
  const float* lng = (const float*)d_in[7];
  const float* lnb = (const float*)d_in[8];
  float* out = (float*)d_out;
  char* ws = (char*)d_ws;

  // Spectral weights (bf16), persistent at base of ws.
  unsigned short* W0s2 = (unsigned short*)ws;
  unsigned short* W2s2 = W0s2 + 4194304;
  unsigned short* Bc2  = W2s2 + 4194304;
  unsigned short* W0s3 = Bc2 + 16777216;
  unsigned short* W2s3 = W0s3 + 1048576;
  unsigned short* Bc3  = W2s3 + 1048576;
  const size_t WT_BYTES = 62914560ull;
  char* chunk_base = ws + WT_BYTES;

  // Per chunk: h1s bf16 Mc*8192 + C2 bf16 Mc*8192 (Z f32 Mc*2048 aliases C2).
  static const int Pcand[10] = {1, 2, 4, 5, 8, 10, 16, 20, 40, 80};
  int P = 80;
  for (int pi = 0; pi < 10; ++pi) {
    size_t mc = (size_t)MROWS / Pcand[pi];
    size_t need = WT_BYTES + mc * 8192 * 2 * 2 + 256;
    if (need <= ws_size) { P = Pcand[pi]; break; }
  }
  const int Mc = MROWS / P;
  unsigned short* h1s = (unsigned short*)chunk_base;                     // Mc x 8192 bf16
  unsigned short* C2  = (unsigned short*)(chunk_base + (size_t)Mc * 8192 * 2);
  float*          Z   = (float*)C2;                                      // Mc x 2048 f32 (alias)

  wtrans_kernel<2048><<<4096, 256, 0, stream>>>(w2, W0s2, W2s2, Bc2);
  wtrans_kernel<512><<<1024, 256, 0, stream>>>(w3, W0s3, W2s3, Bc3);

  for (int c = 0; c < P; ++c) {
    int row0 = c * Mc;
    layer1_kernel<<<dim3(Mc / 32, 8), 256, 0, stream>>>(ins, w1, b1, h1s, row0);
    // L2 spectral: n-tiles [0,16)=V0 (K=2048), [16,32)=V2, [32,64)=Bc (K=4096); bf16 out
    gemm_spec<<<dim3(64, Mc / 128), 256, 0, stream>>>(h1s, W0s2, W2s2, Bc2, nullptr, C2,
                                                      16, 32, 2048, 8192);
    ln_spec_kernel<<<Mc, 256, 0, stream>>>(C2, b2, lng, lnb, h1s);
    // L3 spectral: n-tiles [0,4)=V0', [4,8)=V2', [8,16)=Bc' -> Z f32 (ldc 2048)
    gemm_spec<<<dim3(16, Mc / 128), 256, 0, stream>>>(h1s, W0s3, W2s3, Bc3, Z, nullptr,
                                                      4, 8, 512, 2048);
    out_ep_kernel<<<Mc * 2, 256, 0, stream>>>(Z, b3, out + (size_t)row0 * 2048);
  }
}